// Round 8
// baseline (125.248 us; speedup 1.0000x reference)
//
#include <hip/hip_runtime.h>

// LSTM: B=16384, T=1024, I=1, H=2, C=4.
// 2 lanes per batch element: lane (2e+j) owns hidden unit j of element e.
//
// R8 change vs R7: collapse the per-step serial chain from THREE trans
// stages (exp2 -> rcp(B) -> rcp(D)) to TWO (exp2 -> single rcp).
// Trick: tanh(c') with c' = A/B is evaluated HOMOGENEOUSLY in (A,B):
//   tanh(A/B) = A*P7(A^2,B^2) / (B*Q6(A^2,B^2))    (Pade[7/6])
// so h' = (A~*P) * rcp(B~*Q*Oo) needs ONE rcp, and
//    c' = (A~*Q*Oo) * r reuses the same rcp result OFF the critical path
// (c' is next consumed only after the NEXT step's exp2 stage -> slack).
// B^6 overflow (B up to ~1e14) is prevented by an exponent-only
// normalization (pure int VALU, exact powers of 2, no trans):
//   B~ = mantissa(B) in [1,2)   (and-or on the bit pattern)
//   s  = 2^-E                   (and + sub on the exponent field)
//   A~ = A*s
// Ratio clamp: zA = med3(A~, -5B~, +5B~)  (B~ > 0 always, B >= 1).
//
// Gate rows (PyTorch order): i: 0,1  f: 2,3  g: 4,5  o: 6,7
//   Ei=e^-i, Ef=e^-f, Eo=e^-o (SIG_SCALE folded), Eg=e^{2g} (TANH_SCALE).
//   c' = A/B:  A = (c*Ip)*Gp + (Eg-1)*F,  B = (Gp*F)*Ip,
//   with F=1+Ef, Ip=1+Ei, Gp=1+Eg, Oo=1+Eo.
//   h' = tanh(c')*sigma(o) = zA*P / (B~*Q*Oo),
//   P = ((a+378b)a + 17325b^2)a + 135135b^3,  a=zA^2, b=B~^2
//   Q = ((28a+3150b)a + 62370b^2)a + 135135b^3

typedef float f32x2 __attribute__((ext_vector_type(2)));

static __device__ __forceinline__ float fast_exp2(float x) { return __builtin_amdgcn_exp2f(x); }
static __device__ __forceinline__ float fast_rcp(float x)  { return __builtin_amdgcn_rcpf(x); }

// Swap values between lane pairs (0<->1, 2<->3, ...) via DPP quad_perm.
static __device__ __forceinline__ float dpp_swap1(float v) {
    int i = __builtin_bit_cast(int, v);
    i = __builtin_amdgcn_mov_dpp(i, 0xB1, 0xF, 0xF, false);
    return __builtin_bit_cast(float, i);
}

#define SIG_SCALE  (-1.4426950408889634f)  // -log2(e)
#define TANH_SCALE ( 2.8853900817779268f)  // 2*log2(e)

__global__ __launch_bounds__(64, 1) void lstm_fused4(
    const float* __restrict__ x,      // [B, T, 1]
    const float* __restrict__ W_ih,   // [8, 1]
    const float* __restrict__ W_hh,   // [8, 2]
    const float* __restrict__ b_ih,   // [8]
    const float* __restrict__ b_hh,   // [8]
    const float* __restrict__ W_fc,   // [4, 2]
    const float* __restrict__ b_fc,   // [4]
    float* __restrict__ out,          // [B, 4]
    int T)
{
    const int tid = blockIdx.x * 64 + threadIdx.x;
    const int e   = tid >> 1;          // batch element
    const int j   = tid & 1;           // hidden unit owned by this lane

    // Per-lane scaled weights for my unit's 4 gates (k: 0=i,1=f,2=g,3=o).
    float wihs[4], whm[4], whp[4], bbs[4];
#pragma unroll
    for (int k = 0; k < 4; ++k) {
        const int g = 2 * k + j;                         // gate row
        const float s = (k == 2) ? TANH_SCALE : SIG_SCALE;
        wihs[k] = s * W_ih[g];
        whm[k]  = s * W_hh[2 * g + j];
        whp[k]  = s * W_hh[2 * g + (j ^ 1)];
        bbs[k]  = s * (b_ih[g] + b_hh[g]);
    }

    // Packed views for v_pk_fma_f32 on the pre-activation math.
    f32x2 wihs2[2], whm2[2], whp2[2], bbs2[2];
#pragma unroll
    for (int q = 0; q < 2; ++q) {
        wihs2[q] = f32x2{wihs[2*q], wihs[2*q+1]};
        whm2[q]  = f32x2{whm[2*q],  whm[2*q+1]};
        whp2[q]  = f32x2{whp[2*q],  whp[2*q+1]};
        bbs2[q]  = f32x2{bbs[2*q],  bbs[2*q+1]};
    }

    float hm = 0.f;   // my unit's h
    float hp = 0.f;   // partner unit's h
    float c  = 0.f;   // my unit's c

    const float4* xv = reinterpret_cast<const float4*>(x + (size_t)e * (size_t)T);
    const int nt4 = T >> 2;

    for (int t4 = 0; t4 < nt4; ++t4) {
        const float4 xq = xv[t4];
        const float xs[4] = {xq.x, xq.y, xq.z, xq.w};

        // h-independent x-terms for 4 timesteps (packed fma, off-chain).
        f32x2 xterm[4][2];
#pragma unroll
        for (int u = 0; u < 4; ++u) {
            const f32x2 xu = f32x2{xs[u], xs[u]};
#pragma unroll
            for (int q = 0; q < 2; ++q)
                xterm[u][q] = __builtin_elementwise_fma(xu, wihs2[q], bbs2[q]);
        }

#pragma unroll
        for (int u = 0; u < 4; ++u) {
            const f32x2 hmv = f32x2{hm, hm};
            const f32x2 hpv = f32x2{hp, hp};
            // pre23 first: Eg (pre23.x) heads the critical path.
            const f32x2 pre23 = __builtin_elementwise_fma(
                whm2[1], hmv, __builtin_elementwise_fma(whp2[1], hpv, xterm[u][1]));
            const f32x2 pre01 = __builtin_elementwise_fma(
                whm2[0], hmv, __builtin_elementwise_fma(whp2[0], hpv, xterm[u][0]));

            // Chain-critical exps first: Eg, Ef, Ei; Eo has slack.
            const float Eg = fast_exp2(pre23.x);
            const float Ef = fast_exp2(pre01.y);
            const float Ei = fast_exp2(pre01.x);
            const float Eo = fast_exp2(pre23.y);

            const float Gp  = 1.f + Eg;
            const float F   = 1.f + Ef;
            const float Ip  = 1.f + Ei;
            const float Oo  = 1.f + Eo;

            const float GpF = Gp * F;
            const float GmF = fmaf(Eg, F, -F);             // (Eg-1)(1+Ef)
            const float B   = GpF * Ip;
            const float cp  = c * Ip;
            const float A   = fmaf(cp, Gp, GmF);

            // Exponent-only normalization: B~ in [1,2), A~ = A * 2^-E.
            const unsigned Bi = __builtin_bit_cast(unsigned, B);
            const float Bt = __builtin_bit_cast(float,
                                (Bi & 0x007FFFFFu) | 0x3F800000u);
            const float sc = __builtin_bit_cast(float,
                                0x7F000000u - (Bi & 0x7F800000u));
            const float At = A * sc;

            // Ratio clamp |A~/B~| <= 5 without dividing.
            const float B5 = 5.0f * Bt;
            const float zA = __builtin_amdgcn_fmed3f(At, -B5, B5);

            const float a  = zA * zA;
            const float b  = Bt * Bt;
            const float b2 = b * b;
            const float b3 = b2 * b;
            const float cb3 = 135135.f * b3;

            const float p1 = fmaf(378.f, b, a);
            const float p2 = fmaf(p1, a, 17325.f * b2);
            const float P  = fmaf(p2, a, cb3);

            const float q1 = fmaf(28.f, a, 3150.f * b);
            const float q2 = fmaf(q1, a, 62370.f * b2);
            const float Q  = fmaf(q2, a, cb3);

            const float numer = zA * P;
            const float den   = (Bt * Oo) * Q;
            const float r     = fast_rcp(den);

            hm = numer * r;                    // tanh(c')*sigma(o)

            // c' = A/B = A~/B~ = (A~*Q*Oo)*r — same rcp, off-critical
            // (next consumed only after next step's exp2 stage).
            const float QOo = Q * Oo;
            c = (At * QOo) * r;

            hp = dpp_swap1(hm);                // lane-pair swap
        }
    }

    // Final FC: out[e,:] = h @ W_fc^T + b_fc.  Even lane -> classes 0,1;
    // odd lane -> classes 2,3. Lane pair writes one contiguous 16B row.
    const float h0 = j ? hp : hm;
    const float h1 = j ? hm : hp;
    const int   c0 = 2 * j;
    const float o0 = fmaf(W_fc[2*c0+0], h0, fmaf(W_fc[2*c0+1], h1, b_fc[c0]));
    const float o1 = fmaf(W_fc[2*c0+2], h0, fmaf(W_fc[2*c0+3], h1, b_fc[c0+1]));
    float2 r2; r2.x = o0; r2.y = o1;
    reinterpret_cast<float2*>(out)[e * 2 + j] = r2;
}

extern "C" void kernel_launch(void* const* d_in, const int* in_sizes, int n_in,
                              void* d_out, int out_size, void* d_ws, size_t ws_size,
                              hipStream_t stream) {
    const float* x    = (const float*)d_in[0];
    const float* W_ih = (const float*)d_in[1];
    const float* W_hh = (const float*)d_in[2];
    const float* b_ih = (const float*)d_in[3];
    const float* b_hh = (const float*)d_in[4];
    const float* W_fc = (const float*)d_in[5];
    const float* b_fc = (const float*)d_in[6];
    float* out = (float*)d_out;

    const int T = 1024;
    const int B = in_sizes[0] / T;   // I == 1

    dim3 block(64);
    dim3 grid((B * 2) / 64);         // 2 lanes/element -> 512 waves, 2 waves/CU
    lstm_fused4<<<grid, block, 0, stream>>>(x, W_ih, W_hh, b_ih, b_hh, W_fc, b_fc, out, T);
}

// Round 9
// 113.552 us; speedup vs baseline: 1.1030x; 1.1030x over previous
//
#include <hip/hip_runtime.h>

// LSTM: B=16384, T=1024, I=1, H=2, C=4.
// 2 lanes per batch element: lane (2e+j) owns hidden unit j of element e.
//
// R9 = R7 skeleton (3 serial trans stages: exp2 -> rcp(B) -> rcp(q3)),
// with the VALU links between the stages shortened:
//  1. pre = fma(whp, hp, fma(whm, hm, xterm)): the hm-term FMA overlaps
//     the DPP swap instead of serializing after it.
//  2. Clamp moved OFF the post-rcp chain: zA = med3(A, -5B, +5B) issues
//     during rcp(B) (A and B both ready first); zc = zA*rB is 1 mul.
//  3. Estrin for the Pade[7/6] polys: q3 = (28u+3150)*u^2 + (62370u+135135),
//     p3 = (u+378)*u^2 + (17325u+135135) -> depth 2 after u, not 3.
//  4. sigma(o) = rcp(1+Eo) computed as a PARALLEL third rcp right after Eo
//     (slack-rich) and folded into numer off-chain; removes q3*Oo from the
//     path before the final rcp.
//  5. c = A*rB stays off-critical (consumed after next step's exp2 stage).
//
// Gate rows (PyTorch order): i: 0,1  f: 2,3  g: 4,5  o: 6,7
//   Ei=e^-i, Ef=e^-f, Eo=e^-o (SIG_SCALE folded), Eg=e^{2g} (TANH_SCALE).
//   c' = A/B:  A = (c*Ip)*Gp + (Eg-1)*F,  B = (F*Ip)*Gp,
//   F=1+Ef, Ip=1+Ei, Gp=1+Eg, Oo=1+Eo.
//   h' = tanh(zc)*sigma(o),  zc = med3(A,-5B,5B)*rB,
//   tanh(zc) = zc*p3(zc^2)/q3(zc^2)  (Pade[7/6]).

typedef float f32x2 __attribute__((ext_vector_type(2)));

static __device__ __forceinline__ float fast_exp2(float x) { return __builtin_amdgcn_exp2f(x); }
static __device__ __forceinline__ float fast_rcp(float x)  { return __builtin_amdgcn_rcpf(x); }

// Swap values between lane pairs (0<->1, 2<->3, ...) via DPP quad_perm.
static __device__ __forceinline__ float dpp_swap1(float v) {
    int i = __builtin_bit_cast(int, v);
    i = __builtin_amdgcn_mov_dpp(i, 0xB1, 0xF, 0xF, false);
    return __builtin_bit_cast(float, i);
}

#define SIG_SCALE  (-1.4426950408889634f)  // -log2(e)
#define TANH_SCALE ( 2.8853900817779268f)  // 2*log2(e)

__global__ __launch_bounds__(64, 1) void lstm_fused5(
    const float* __restrict__ x,      // [B, T, 1]
    const float* __restrict__ W_ih,   // [8, 1]
    const float* __restrict__ W_hh,   // [8, 2]
    const float* __restrict__ b_ih,   // [8]
    const float* __restrict__ b_hh,   // [8]
    const float* __restrict__ W_fc,   // [4, 2]
    const float* __restrict__ b_fc,   // [4]
    float* __restrict__ out,          // [B, 4]
    int T)
{
    const int tid = blockIdx.x * 64 + threadIdx.x;
    const int e   = tid >> 1;          // batch element
    const int j   = tid & 1;           // hidden unit owned by this lane

    // Per-lane scaled weights for my unit's 4 gates (k: 0=i,1=f,2=g,3=o).
    // whm multiplies MY h, whp multiplies my PARTNER's h.
    float wihs[4], whm[4], whp[4], bbs[4];
#pragma unroll
    for (int k = 0; k < 4; ++k) {
        const int g = 2 * k + j;                         // gate row
        const float s = (k == 2) ? TANH_SCALE : SIG_SCALE;
        wihs[k] = s * W_ih[g];
        whm[k]  = s * W_hh[2 * g + j];
        whp[k]  = s * W_hh[2 * g + (j ^ 1)];
        bbs[k]  = s * (b_ih[g] + b_hh[g]);
    }

    f32x2 wihs2[2], whm2[2], whp2[2], bbs2[2];
#pragma unroll
    for (int q = 0; q < 2; ++q) {
        wihs2[q] = f32x2{wihs[2*q], wihs[2*q+1]};
        whm2[q]  = f32x2{whm[2*q],  whm[2*q+1]};
        whp2[q]  = f32x2{whp[2*q],  whp[2*q+1]};
        bbs2[q]  = f32x2{bbs[2*q],  bbs[2*q+1]};
    }

    float hm = 0.f;   // my unit's h
    float hp = 0.f;   // partner unit's h
    float c  = 0.f;   // my unit's c

    const float4* xv = reinterpret_cast<const float4*>(x + (size_t)e * (size_t)T);
    const int nt4 = T >> 2;

    for (int t4 = 0; t4 < nt4; ++t4) {
        const float4 xq = xv[t4];
        const float xs[4] = {xq.x, xq.y, xq.z, xq.w};

        // h-independent x-terms for 4 timesteps (off-chain).
        f32x2 xterm[4][2];
#pragma unroll
        for (int u = 0; u < 4; ++u) {
            const f32x2 xu = f32x2{xs[u], xs[u]};
#pragma unroll
            for (int q = 0; q < 2; ++q)
                xterm[u][q] = __builtin_elementwise_fma(xu, wihs2[q], bbs2[q]);
        }

#pragma unroll
        for (int u = 0; u < 4; ++u) {
            const f32x2 hm2 = f32x2{hm, hm};
            const f32x2 hp2 = f32x2{hp, hp};
            // hm-term first: overlaps the DPP that produced hp.
            const f32x2 in23 = __builtin_elementwise_fma(whm2[1], hm2, xterm[u][1]);
            const f32x2 in01 = __builtin_elementwise_fma(whm2[0], hm2, xterm[u][0]);
            const f32x2 pre23 = __builtin_elementwise_fma(whp2[1], hp2, in23);
            const f32x2 pre01 = __builtin_elementwise_fma(whp2[0], hp2, in01);

            // Chain-critical exp first: Eg heads the path.
            const float Eg = fast_exp2(pre23.x);
            const float Ef = fast_exp2(pre01.y);
            const float Ei = fast_exp2(pre01.x);
            const float Eo = fast_exp2(pre23.y);

            const float Gp  = 1.f + Eg;
            const float F   = 1.f + Ef;
            const float Ip  = 1.f + Ei;
            const float Oo  = 1.f + Eo;

            const float FIp = F * Ip;
            const float GmF = fmaf(Eg, F, -F);             // (Eg-1)(1+Ef)
            const float B   = FIp * Gp;
            const float rB  = fast_rcp(B);                 // trans stage 2
            const float rOo = fast_rcp(Oo);                // sigma(o), parallel

            const float cp  = c * Ip;
            const float A   = fmaf(cp, Gp, GmF);
            const float B5  = 5.0f * B;
            const float zA  = __builtin_amdgcn_fmed3f(A, -B5, B5); // during rcp

            c = A * rB;                                    // next cell, off-path
            const float zc = zA * rB;                      // clamped c'

            const float uu = zc * zc;
            const float u2 = uu * uu;
            // Estrin, depth 2 after uu:
            const float qa = fmaf(28.f, uu, 3150.f);
            const float qL = fmaf(62370.f, uu, 135135.f);
            const float q3 = fmaf(qa, u2, qL);
            const float pa = uu + 378.f;
            const float pL = fmaf(17325.f, uu, 135135.f);
            const float p3 = fmaf(pa, u2, pL);

            const float rq = fast_rcp(q3);                 // trans stage 3
            const float numerS = (zc * p3) * rOo;          // ready before rq
            hm = numerS * rq;                              // tanh(c')*sigma(o)

            hp = dpp_swap1(hm);                            // lane-pair swap
        }
    }

    // Final FC: out[e,:] = h @ W_fc^T + b_fc.  Even lane -> classes 0,1;
    // odd lane -> classes 2,3. Lane pair writes one contiguous 16B row.
    const float h0 = j ? hp : hm;
    const float h1 = j ? hm : hp;
    const int   c0 = 2 * j;
    const float o0 = fmaf(W_fc[2*c0+0], h0, fmaf(W_fc[2*c0+1], h1, b_fc[c0]));
    const float o1 = fmaf(W_fc[2*c0+2], h0, fmaf(W_fc[2*c0+3], h1, b_fc[c0+1]));
    float2 r2; r2.x = o0; r2.y = o1;
    reinterpret_cast<float2*>(out)[e * 2 + j] = r2;
}

extern "C" void kernel_launch(void* const* d_in, const int* in_sizes, int n_in,
                              void* d_out, int out_size, void* d_ws, size_t ws_size,
                              hipStream_t stream) {
    const float* x    = (const float*)d_in[0];
    const float* W_ih = (const float*)d_in[1];
    const float* W_hh = (const float*)d_in[2];
    const float* b_ih = (const float*)d_in[3];
    const float* b_hh = (const float*)d_in[4];
    const float* W_fc = (const float*)d_in[5];
    const float* b_fc = (const float*)d_in[6];
    float* out = (float*)d_out;

    const int T = 1024;
    const int B = in_sizes[0] / T;   // I == 1

    dim3 block(64);
    dim3 grid((B * 2) / 64);         // 2 lanes/element -> 512 waves, 2 waves/CU
    lstm_fused5<<<grid, block, 0, stream>>>(x, W_ih, W_hh, b_ih, b_hh, W_fc, b_fc, out, T);
}

// Round 10
// 104.135 us; speedup vs baseline: 1.2027x; 1.0904x over previous
//
#include <hip/hip_runtime.h>

// LSTM: B=16384, T=1024, I=1, H=2, C=4.
// 2 lanes per batch element: lane (2e+j) owns hidden unit j of element e.
//
// R10 = EXACT R7 base (verified 105.9 us, 248 cy/step) + two surgical cuts
// on the post-rcp(B) dependency path, nothing else changed:
//  1. Clamp moved BEFORE the rcp: zA = med3(A, -4B, +4B) issues during the
//     rcp(B) wait (A and B are both ready pre-rcp); post-rcp path is just
//     zc = zA*rB. (R9 bundled this with a harmful extra rcp; isolated here.)
//  2. Pade[5/4] tanh instead of [7/6]: z(945+105z^2+z^4)/(945+420z^2+15z^4),
//     Horner depth 2 instead of 3 (one fewer chain link). Max err 2.3e-3 at
//     the +-4 clamp, <=4e-4 interior — threshold is 1.4e-2.
// NO new trans ops (R8/R9 lesson: the in-order trans pipe punishes "slack"
// rcps and extra serial VALU far more than the dataflow model predicts).
//
// Gate rows (PyTorch order): i: 0,1  f: 2,3  g: 4,5  o: 6,7
//   Ei=e^-i, Ef=e^-f, Eo=e^-o (SIG_SCALE folded), Eg=e^{2g} (TANH_SCALE).
//   c' = A/B:  A = (c*Ip)*Gp + (Eg-1)*F,  B = (Gp*F)*Ip,
//   F=1+Ef, Ip=1+Ei, Gp=1+Eg, Oo=1+Eo.
//   h' = tanh(zc)*sigma(o), zc = med3(A,-4B,4B)*rB,
//   tanh(zc) = zc*(zc^4+105zc^2+945)/(15zc^4+420zc^2+945),  D = q*Oo.

typedef float f32x2 __attribute__((ext_vector_type(2)));

static __device__ __forceinline__ float fast_exp2(float x) { return __builtin_amdgcn_exp2f(x); }
static __device__ __forceinline__ float fast_rcp(float x)  { return __builtin_amdgcn_rcpf(x); }

// Swap values between lane pairs (0<->1, 2<->3, ...) via DPP quad_perm.
static __device__ __forceinline__ float dpp_swap1(float v) {
    int i = __builtin_bit_cast(int, v);
    i = __builtin_amdgcn_mov_dpp(i, 0xB1, 0xF, 0xF, false);
    return __builtin_bit_cast(float, i);
}

#define SIG_SCALE  (-1.4426950408889634f)  // -log2(e)
#define TANH_SCALE ( 2.8853900817779268f)  // 2*log2(e)

__global__ __launch_bounds__(64, 1) void lstm_fused6(
    const float* __restrict__ x,      // [B, T, 1]
    const float* __restrict__ W_ih,   // [8, 1]
    const float* __restrict__ W_hh,   // [8, 2]
    const float* __restrict__ b_ih,   // [8]
    const float* __restrict__ b_hh,   // [8]
    const float* __restrict__ W_fc,   // [4, 2]
    const float* __restrict__ b_fc,   // [4]
    float* __restrict__ out,          // [B, 4]
    int T)
{
    const int tid = blockIdx.x * 64 + threadIdx.x;
    const int e   = tid >> 1;          // batch element
    const int j   = tid & 1;           // hidden unit owned by this lane

    // Per-lane scaled weights for my unit's 4 gates (k: 0=i,1=f,2=g,3=o).
    // whm multiplies MY h, whp multiplies my PARTNER's h.
    float wihs[4], whm[4], whp[4], bbs[4];
#pragma unroll
    for (int k = 0; k < 4; ++k) {
        const int g = 2 * k + j;                         // gate row
        const float s = (k == 2) ? TANH_SCALE : SIG_SCALE;
        wihs[k] = s * W_ih[g];
        whm[k]  = s * W_hh[2 * g + j];
        whp[k]  = s * W_hh[2 * g + (j ^ 1)];
        bbs[k]  = s * (b_ih[g] + b_hh[g]);
    }

    // Packed views for v_pk_fma_f32 on the pre-activation math.
    f32x2 wihs2[2], whm2[2], whp2[2], bbs2[2];
#pragma unroll
    for (int q = 0; q < 2; ++q) {
        wihs2[q] = f32x2{wihs[2*q], wihs[2*q+1]};
        whm2[q]  = f32x2{whm[2*q],  whm[2*q+1]};
        whp2[q]  = f32x2{whp[2*q],  whp[2*q+1]};
        bbs2[q]  = f32x2{bbs[2*q],  bbs[2*q+1]};
    }

    float hm = 0.f;   // my unit's h
    float hp = 0.f;   // partner unit's h
    float c  = 0.f;   // my unit's c

    const float4* xv = reinterpret_cast<const float4*>(x + (size_t)e * (size_t)T);
    const int nt4 = T >> 2;

    for (int t4 = 0; t4 < nt4; ++t4) {
        const float4 xq = xv[t4];
        const float xs[4] = {xq.x, xq.y, xq.z, xq.w};

        // h-independent x-terms for 4 timesteps (packed fma, off-chain).
        f32x2 xterm[4][2];
#pragma unroll
        for (int u = 0; u < 4; ++u) {
            const f32x2 xu = f32x2{xs[u], xs[u]};
#pragma unroll
            for (int q = 0; q < 2; ++q)
                xterm[u][q] = __builtin_elementwise_fma(xu, wihs2[q], bbs2[q]);
        }

#pragma unroll
        for (int u = 0; u < 4; ++u) {
            const f32x2 hmv = f32x2{hm, hm};
            const f32x2 hpv = f32x2{hp, hp};
            // pre23 first: Eg (pre23.x) heads the critical path.
            const f32x2 pre23 = __builtin_elementwise_fma(
                whm2[1], hmv, __builtin_elementwise_fma(whp2[1], hpv, xterm[u][1]));
            const f32x2 pre01 = __builtin_elementwise_fma(
                whm2[0], hmv, __builtin_elementwise_fma(whp2[0], hpv, xterm[u][0]));

            // Chain-critical exps first: Eg, Ef, Ei; Eo has slack.
            const float Eg = fast_exp2(pre23.x);
            const float Ef = fast_exp2(pre01.y);
            const float Ei = fast_exp2(pre01.x);
            const float Eo = fast_exp2(pre23.y);

            const float Gp  = 1.f + Eg;
            const float F   = 1.f + Ef;
            const float Ip  = 1.f + Ei;
            const float Oo  = 1.f + Eo;

            const float GpF = Gp * F;
            const float GmF = fmaf(Eg, F, -F);             // (Eg-1)(1+Ef)
            const float B   = GpF * Ip;
            const float cp  = c * Ip;
            const float A   = fmaf(cp, Gp, GmF);

            // Clamp in (A,B) space BEFORE the rcp (issues during rcp wait).
            const float B4  = 4.0f * B;                    // 4.0 = inline const
            const float zA  = __builtin_amdgcn_fmed3f(A, -B4, B4);

            const float rB  = fast_rcp(B);                 // trans stage 2
            c = A * rB;                                    // next cell, off-path
            const float zc = zA * rB;                      // clamped c'

            // Pade[5/4] tanh, Horner depth 2 from uu.
            const float uu = zc * zc;
            const float p  = fmaf(uu + 105.f, uu, 945.f);
            const float q  = fmaf(fmaf(15.f, uu, 420.f), uu, 945.f);
            const float numer = zc * p;
            const float D  = q * Oo;
            const float rD = fast_rcp(D);                  // trans stage 3
            hm = numer * rD;                               // tanh(c')*sigma(o)

            hp = dpp_swap1(hm);                            // lane-pair swap
        }
    }

    // Final FC: out[e,:] = h @ W_fc^T + b_fc.  Even lane -> classes 0,1;
    // odd lane -> classes 2,3. Lane pair writes one contiguous 16B row.
    const float h0 = j ? hp : hm;
    const float h1 = j ? hm : hp;
    const int   c0 = 2 * j;
    const float o0 = fmaf(W_fc[2*c0+0], h0, fmaf(W_fc[2*c0+1], h1, b_fc[c0]));
    const float o1 = fmaf(W_fc[2*c0+2], h0, fmaf(W_fc[2*c0+3], h1, b_fc[c0+1]));
    float2 r2; r2.x = o0; r2.y = o1;
    reinterpret_cast<float2*>(out)[e * 2 + j] = r2;
}

extern "C" void kernel_launch(void* const* d_in, const int* in_sizes, int n_in,
                              void* d_out, int out_size, void* d_ws, size_t ws_size,
                              hipStream_t stream) {
    const float* x    = (const float*)d_in[0];
    const float* W_ih = (const float*)d_in[1];
    const float* W_hh = (const float*)d_in[2];
    const float* b_ih = (const float*)d_in[3];
    const float* b_hh = (const float*)d_in[4];
    const float* W_fc = (const float*)d_in[5];
    const float* b_fc = (const float*)d_in[6];
    float* out = (float*)d_out;

    const int T = 1024;
    const int B = in_sizes[0] / T;   // I == 1

    dim3 block(64);
    dim3 grid((B * 2) / 64);         // 2 lanes/element -> 512 waves, 2 waves/CU
    lstm_fused6<<<grid, block, 0, stream>>>(x, W_ih, W_hh, b_ih, b_hh, W_fc, b_fc, out, T);
}